// Round 14
// baseline (205.815 us; speedup 1.0000x reference)
//
#include <hip/hip_runtime.h>

#define L_DIM 2048
#define B_DIM 8
#define DD    1024
#define M_DIM 16384     // L*B
#define N_DIM 3072      // 3*D
#define K_DIM 1024
#define CH    8192      // B*D channels
#define CH8   1024      // CH/8 (vec8 units per l-step)
#define NSEG  128
#define LSEG  16
#define LN_EPS 1e-5f

typedef __attribute__((ext_vector_type(8))) short bf16x8;
typedef __attribute__((ext_vector_type(8))) unsigned short u16x8;
typedef __attribute__((ext_vector_type(4))) float f32x4;

__device__ __forceinline__ unsigned short f2bf(float f){
  unsigned u = __float_as_uint(f);
  u += 0x7fffu + ((u >> 16) & 1u);
  return (unsigned short)(u >> 16);
}
__device__ __forceinline__ float bf2f(unsigned short h){
  return __uint_as_float(((unsigned)h) << 16);
}
__device__ __forceinline__ float fsigmoid(float z){ return 1.0f/(1.0f + __expf(-z)); }
__device__ __forceinline__ float ftanh(float z){ return 1.0f - 2.0f/(1.0f + __expf(2.0f*z)); }

// ------- LayerNorm: wave-per-row, 4 rows/block, no barriers -------
__global__ __launch_bounds__(256) void ln_kernel(const float* __restrict__ x,
                                                 const float* __restrict__ g,
                                                 const float* __restrict__ bta,
                                                 unsigned short* __restrict__ xn)
{
  int tid  = threadIdx.x;
  int wave = tid >> 6, lane = tid & 63;
  int row  = blockIdx.x * 4 + wave;
  const float4* xr = (const float4*)(x + (size_t)row * DD);
  float4 v[4];
  #pragma unroll
  for (int k = 0; k < 4; k++) v[k] = xr[lane + k * 64];
  float s = 0.f, sq = 0.f;
  #pragma unroll
  for (int k = 0; k < 4; k++) {
    s  += v[k].x + v[k].y + v[k].z + v[k].w;
    sq += v[k].x*v[k].x + v[k].y*v[k].y + v[k].z*v[k].z + v[k].w*v[k].w;
  }
  #pragma unroll
  for (int off = 32; off > 0; off >>= 1) {
    s  += __shfl_down(s,  off, 64);
    sq += __shfl_down(sq, off, 64);
  }
  s  = __shfl(s,  0, 64);
  sq = __shfl(sq, 0, 64);
  float mean = s * (1.0f / DD);
  float var  = sq * (1.0f / DD) - mean * mean;
  float rstd = rsqrtf(var + LN_EPS);
  ushort4* xo = (ushort4*)(xn + (size_t)row * DD);
  #pragma unroll
  for (int k = 0; k < 4; k++) {
    float4 gg = ((const float4*)g)[lane + k * 64];
    float4 bb = ((const float4*)bta)[lane + k * 64];
    ushort4 o;
    o.x = f2bf((v[k].x - mean) * rstd * gg.x + bb.x);
    o.y = f2bf((v[k].y - mean) * rstd * gg.y + bb.y);
    o.z = f2bf((v[k].z - mean) * rstd * gg.z + bb.z);
    o.w = f2bf((v[k].w - mean) * rstd * gg.w + bb.w);
    xo[lane + k * 64] = o;
  }
}

// ---------------- W fp32 [3072,1024] -> bf16 same layout ----------------
__global__ __launch_bounds__(256) void wconv_kernel(const float* __restrict__ W,
                                                    unsigned short* __restrict__ wb)
{
  int gid = blockIdx.x * 256 + threadIdx.x;
  float4 v = ((const float4*)W)[gid];
  ushort4 o;
  o.x = f2bf(v.x); o.y = f2bf(v.y); o.z = f2bf(v.z); o.w = f2bf(v.w);
  ((ushort4*)wb)[gid] = o;
}

// ---------------- GEMM: ufr = xn * W^T + b, fused activations ----------------
// R13 base (counted vmcnt + counted lgkm, A-dbuf + B-single 80 KB, 2 blocks/CU,
// 2Mx4N waves, bm-fastest grid). Two changes vs R13:
//  (1) s_setprio REMOVED from the K-loop: R13 is a barrier-lockstep structure;
//      per m190/m218b setprio only pays with wave role-split (8-phase) and was
//      negative on lockstep GEMM (cross-block issue starvation).
//  (2) Epilogue merged 4 chunks -> 2 chunks of 128 rows (34.8 KB <= 80 KB
//      already allocated): 9 -> 5 barriers in the serial tail.
#define BM 256
#define BN 128
#define BK 64
#define NT 16          // K_DIM / BK
#define LDP 136        // epilogue chunk leading dim (shorts)

#define GLDS16(gp, lp) __builtin_amdgcn_global_load_lds( \
    (const __attribute__((address_space(1))) void*)(gp), \
    (__attribute__((address_space(3))) void*)(lp), 16, 0, 0)

#define SBAR()   __builtin_amdgcn_s_barrier()
#define SCHED0() __builtin_amdgcn_sched_barrier(0)
#define WAIT_LGKM(N) do { asm volatile("s_waitcnt lgkmcnt(" #N ")" ::: "memory"); SCHED0(); } while(0)
#define WAIT_VM(N)   do { asm volatile("s_waitcnt vmcnt(" #N ")" ::: "memory"); SCHED0(); } while(0)

// raw ds_read_b128: invisible to alias analysis; ordering carried by the
// explicit lgkm/vm waits + barriers (volatile asm keeps mutual program order).
#define DSR(dst, addr, IMM) \
  asm volatile("ds_read_b128 %0, %1 offset:" #IMM : "=v"(dst) : "v"(addr))

#define MFMA(a, b, c) __builtin_amdgcn_mfma_f32_16x16x32_bf16((a), (b), (c), 0, 0, 0)

__global__ __launch_bounds__(512, 4) void gemm_gates(const unsigned short* __restrict__ A,
                                                     const unsigned short* __restrict__ Bw,
                                                     const float* __restrict__ bias,
                                                     unsigned short* __restrict__ u_t,
                                                     unsigned short* __restrict__ f_g,
                                                     unsigned short* __restrict__ r_g)
{
  // shorts: sA buf0 [0,16384) buf1 [16384,32768); sB [32768,40960). 81,920 B.
  __shared__ unsigned short smem[40960];
  const int tid  = threadIdx.x;
  const int wave = tid >> 6, lane = tid & 63;

  const int bm0 = blockIdx.x * BM;       // bx = bm fastest (R6/R11 locality)
  const int bn0 = blockIdx.y * BN;

  f32x4 zero = {0.f, 0.f, 0.f, 0.f};
  f32x4 acc[8][2];
  #pragma unroll
  for (int i = 0; i < 8; i++)
    #pragma unroll
    for (int j = 0; j < 2; j++) acc[i][j] = zero;

  const int q8  = lane >> 3;
  const int rr8 = lane & 7;
  const int sch = rr8 ^ q8;              // XOR swizzle source chunk
  const unsigned short* a_lane = A  + (size_t)(bm0 + wave * 32 + q8) * K_DIM + sch * 8;
  const unsigned short* b_lane = Bw + (size_t)(bn0 + wave * 16 + q8) * K_DIM + sch * 8;

  const int wm = (wave >> 2) * 128, wn = (wave & 3) * 32;   // 2M x 4N (R11)
  const int fm = lane & 15, quad = lane >> 4;
  const int f7 = fm & 7;

// stage A K-tile T into dbuf half BUF: 4 gload_lds per wave (HBM-class)
#define STAGE_A(BUF, T) do { \
  GLDS16(a_lane + (size_t)(T) * BK,                      &smem[(BUF)*16384 + (wave * 32 +  0) * BK]); \
  GLDS16(a_lane + (size_t)(T) * BK + (size_t) 8 * K_DIM, &smem[(BUF)*16384 + (wave * 32 +  8) * BK]); \
  GLDS16(a_lane + (size_t)(T) * BK + (size_t)16 * K_DIM, &smem[(BUF)*16384 + (wave * 32 + 16) * BK]); \
  GLDS16(a_lane + (size_t)(T) * BK + (size_t)24 * K_DIM, &smem[(BUF)*16384 + (wave * 32 + 24) * BK]); \
} while(0)

// stage B K-tile T into the single B buffer: 2 gload_lds per wave (L2-hit)
#define STAGE_B(T) do { \
  GLDS16(b_lane + (size_t)(T) * BK,                      &smem[32768 + (wave * 16 + 0) * BK]); \
  GLDS16(b_lane + (size_t)(T) * BK + (size_t) 8 * K_DIM, &smem[32768 + (wave * 16 + 8) * BK]); \
} while(0)

// one kk half-step (R13 order, counted-lgkm waits): 2 B + 8 A ds_read_b128,
// 4 waits at lgkm(2)/(0)/(2)/(0), 4x4 MFMA. Live frags: 6 (24 VGPR).
#define COMPUTE_KK(AADDR, BADDR) do { \
  bf16x8 b0f, b1f, a0f, a1f, a2f, a3f; \
  DSR(b0f, (BADDR), 0); DSR(b1f, (BADDR), 2048); \
  DSR(a0f, (AADDR), 0);    DSR(a1f, (AADDR), 2048); \
  DSR(a2f, (AADDR), 4096); DSR(a3f, (AADDR), 6144); \
  WAIT_LGKM(2); /* b0,b1,a0,a1 landed; a2,a3 in flight under next 4 MFMA */ \
  acc[0][0] = MFMA(a0f, b0f, acc[0][0]); acc[0][1] = MFMA(a0f, b1f, acc[0][1]); \
  acc[1][0] = MFMA(a1f, b0f, acc[1][0]); acc[1][1] = MFMA(a1f, b1f, acc[1][1]); \
  WAIT_LGKM(0); /* a2,a3 landed (mostly covered) */ \
  acc[2][0] = MFMA(a2f, b0f, acc[2][0]); acc[2][1] = MFMA(a2f, b1f, acc[2][1]); \
  acc[3][0] = MFMA(a3f, b0f, acc[3][0]); acc[3][1] = MFMA(a3f, b1f, acc[3][1]); \
  DSR(a0f, (AADDR), 8192);  DSR(a1f, (AADDR), 10240); \
  DSR(a2f, (AADDR), 12288); DSR(a3f, (AADDR), 14336); \
  WAIT_LGKM(2); /* new a0,a1 landed; a2,a3 under next 4 MFMA */ \
  acc[4][0] = MFMA(a0f, b0f, acc[4][0]); acc[4][1] = MFMA(a0f, b1f, acc[4][1]); \
  acc[5][0] = MFMA(a1f, b0f, acc[5][0]); acc[5][1] = MFMA(a1f, b1f, acc[5][1]); \
  WAIT_LGKM(0); \
  acc[6][0] = MFMA(a2f, b0f, acc[6][0]); acc[6][1] = MFMA(a2f, b1f, acc[6][1]); \
  acc[7][0] = MFMA(a3f, b0f, acc[7][0]); acc[7][1] = MFMA(a3f, b1f, acc[7][1]); \
} while(0)

  // fragment byte bases (XOR-swizzle read side folded in): slot0 = (quad^f7)*16
  const unsigned slot0 = (unsigned)((quad ^ f7) << 4);
  const unsigned aBase = (unsigned)((wm + fm) * 128) + slot0;            // in sA buf
  const unsigned bBase = 65536u + (unsigned)((wn + fm) * 128) + slot0;   // in sB

  // ---- prologue: B(0)[2], A(0)[4], A(1)[4]; wait oldest 6 (B0+A0); A1 flies ----
  STAGE_B(0);
  STAGE_A(0, 0);
  STAGE_A(1, 1);
  WAIT_VM(4);
  SBAR();

  #pragma unroll
  for (int t = 0; t < NT; ++t) {
    const int cb = t & 1;
    const unsigned cbB = (unsigned)(cb * 32768);
    COMPUTE_KK(cbB + aBase,         bBase);          // kk = 0
    COMPUTE_KK((cbB + aBase) ^ 64u, bBase ^ 64u);    // kk = 1 (slot ^ 4 -> byte ^ 64)
    SCHED0();
    SBAR();                                // all waves done reading sB & sA[cb]
    if (t + 1 < NT) STAGE_B(t + 1);        // 2 loads, L2-hit
    if (t + 2 < NT) STAGE_A(cb, t + 2);    // 4 loads, HBM, fly across next step
    SCHED0();
    if      (t <  NT - 2) WAIT_VM(4);      // A(t+1)+B(t+1) landed; A(t+2) flying
    else if (t == NT - 2) WAIT_VM(0);      // tail: everything landed
    SBAR();
  }
  __syncthreads();

  const int slice = bn0 >> 10;
  const int nd0   = bn0 & 1023;
  unsigned short* dst = (slice == 0) ? u_t : ((slice == 1) ? f_g : r_g);

  // two-chunk epilogue: rows [h*128, h*128+128) staged in 128*LDP shorts
  // (34,816 B <= 81,920 allocated). Chunk h produced by waves (wave>>2)==h
  // (4 waves x 8 mi = 128 rows), cols split by wn (4 x 32).
  #pragma unroll
  for (int h = 0; h < 2; ++h) {
    if ((wave >> 2) == h) {
      #pragma unroll
      for (int ni = 0; ni < 2; ni++) {
        int lcol = wn + ni * 16 + fm;
        float bia = bias[bn0 + lcol];
        #pragma unroll
        for (int mi = 0; mi < 8; mi++) {
          #pragma unroll
          for (int reg = 0; reg < 4; reg++) {
            int lrow = mi * 16 + quad * 4 + reg;       // 0..127 within chunk
            float v = acc[mi][ni][reg] + bia;
            float act = (slice == 0) ? ftanh(v) : fsigmoid(v);
            smem[lrow * LDP + lcol] = f2bf(act);
          }
        }
      }
    }
    __syncthreads();
    #pragma unroll
    for (int it = 0; it < 4; ++it) {
      int row = it * 32 + (tid >> 4);                  // 0..127
      int cc  = (tid & 15) * 8;                        // 0..120
      u16x8 v = *(const u16x8*)&smem[row * LDP + cc];
      *(u16x8*)(dst + (size_t)(bm0 + h * 128 + row) * DD + nd0 + cc) = v;
    }
    __syncthreads();
  }
}

// ---- scan pass 1: per-segment affine summary, vec8 channels, 16B loads ----
// segment = 16 l-steps; P,E stored bf16 [NSEG][CH]
__global__ __launch_bounds__(256) void scan_pass1(const unsigned short* __restrict__ f_g,
                                                  const unsigned short* __restrict__ u_t,
                                                  unsigned short* __restrict__ P,
                                                  unsigned short* __restrict__ E)
{
  int vc8 = blockIdx.x * 256 + threadIdx.x;   // 0..1023
  int seg = blockIdx.y;                       // 0..127
  const u16x8* f8 = (const u16x8*)f_g;
  const u16x8* u8 = (const u16x8*)u_t;
  size_t g = (size_t)(seg * LSEG) * CH8 + vc8;
  float p[8], e[8];
  #pragma unroll
  for (int k = 0; k < 8; k++) { p[k] = 1.f; e[k] = 0.f; }
  #pragma unroll 4
  for (int i = 0; i < LSEG; i++) {
    u16x8 ff = f8[g];
    u16x8 uu = u8[g];
    #pragma unroll
    for (int k = 0; k < 8; k++) {
      float fv = bf2f(ff[k]);
      e[k] = fv * e[k] + (1.f - fv) * bf2f(uu[k]);
      p[k] *= fv;
    }
    g += CH8;
  }
  u16x8 pv, ev;
  #pragma unroll
  for (int k = 0; k < 8; k++) { pv[k] = f2bf(p[k]); ev[k] = f2bf(e[k]); }
  ((u16x8*)P)[(size_t)seg * CH8 + vc8] = pv;
  ((u16x8*)E)[(size_t)seg * CH8 + vc8] = ev;
}

// ---- scan pass 2: scan 128 segment summaries per channel ----
__global__ __launch_bounds__(128) void scan_pass2(const unsigned short* __restrict__ P,
                                                  const unsigned short* __restrict__ E,
                                                  const float* __restrict__ c0,
                                                  float* __restrict__ Cini,
                                                  float* __restrict__ lastc)
{
  int ch = blockIdx.x * 128 + threadIdx.x;    // 64 blocks x 128
  float c = c0[ch];
  #pragma unroll 8
  for (int s = 0; s < NSEG; s++) {
    Cini[(size_t)s * CH + ch] = c;
    c = bf2f(P[(size_t)s * CH + ch]) * c + bf2f(E[(size_t)s * CH + ch]);
  }
  lastc[ch] = c;
}

// ---- scan pass 3: replay with true init + fused output, vec8, 16B loads ----
__global__ __launch_bounds__(256) void scan_pass3(const unsigned short* __restrict__ f_g,
                                                  const unsigned short* __restrict__ u_t,
                                                  const unsigned short* __restrict__ r_g,
                                                  const float* __restrict__ x,
                                                  const unsigned short* __restrict__ xn,
                                                  const float* __restrict__ Cini,
                                                  float* __restrict__ out)
{
  int vc8 = blockIdx.x * 256 + threadIdx.x;   // 0..1023
  int seg = blockIdx.y;                       // 0..127
  const u16x8* f8 = (const u16x8*)f_g;
  const u16x8* u8 = (const u16x8*)u_t;
  const u16x8* r8 = (const u16x8*)r_g;
  const u16x8* n8 = (const u16x8*)xn;
  const float4* x4 = (const float4*)x;
  float4* o4 = (float4*)out;
  float c[8];
  {
    const float4* C4 = (const float4*)Cini;
    size_t ci = (size_t)seg * (CH / 4) + (size_t)vc8 * 2;
    float4 ca = C4[ci], cb = C4[ci + 1];
    c[0]=ca.x; c[1]=ca.y; c[2]=ca.z; c[3]=ca.w;
    c[4]=cb.x; c[5]=cb.y; c[6]=cb.z; c[7]=cb.w;
  }
  size_t g = (size_t)(seg * LSEG) * CH8 + vc8;
  #pragma unroll 2
  for (int i = 0; i < LSEG; i++) {
    u16x8 ff = f8[g];
    u16x8 uu = u8[g];
    u16x8 rr = r8[g];
    u16x8 nn = n8[g];
    size_t xi = g * 2;                 // float4 index (8 floats = 2 float4)
    float4 xa = x4[xi], xb = x4[xi + 1];
    float ov[8];
    #pragma unroll
    for (int k = 0; k < 8; k++) {
      float fv = bf2f(ff[k]);
      c[k] = fv * c[k] + (1.f - fv) * bf2f(uu[k]);
      float rv = bf2f(rr[k]);
      ov[k] = rv * ftanh(c[k]) + (1.f - rv) * bf2f(nn[k]);
    }
    o4[xi]     = (float4){xa.x + ov[0], xa.y + ov[1], xa.z + ov[2], xa.w + ov[3]};
    o4[xi + 1] = (float4){xb.x + ov[4], xb.y + ov[5], xb.z + ov[6], xb.w + ov[7]};
    g += CH8;
  }
}

extern "C" void kernel_launch(void* const* d_in, const int* in_sizes, int n_in,
                              void* d_out, int out_size, void* d_ws, size_t ws_size,
                              hipStream_t stream) {
  const float* x    = (const float*)d_in[0];
  const float* c0   = (const float*)d_in[1];
  const float* W    = (const float*)d_in[2];
  const float* bias = (const float*)d_in[3];
  const float* ln_g = (const float*)d_in[4];
  const float* ln_b = (const float*)d_in[5];
  float* out = (float*)d_out;

  char* ws = (char*)d_ws;
  unsigned short* xn  = (unsigned short*)(ws);                 // 33,554,432 B
  unsigned short* wb  = (unsigned short*)(ws + 33554432ULL);   //  6,291,456 B (dead after gemm)
  unsigned short* u_t = (unsigned short*)(ws + 39845888ULL);   // 33,554,432 B
  unsigned short* f_g = (unsigned short*)(ws + 73400320ULL);   // 33,554,432 B
  unsigned short* r_g = (unsigned short*)(ws + 106954752ULL);  // 33,554,432 B
  // P,E (bf16, 2 MB each) reuse wb's region after gemm completes:
  unsigned short* Pseg = (unsigned short*)(ws + 33554432ULL);  // 2,097,152 B
  unsigned short* Eseg = (unsigned short*)(ws + 35651584ULL);  // 2,097,152 B
  float* Cini = (float*)(ws + 140509184ULL);                   // 4,194,304 B (ends 144,703,488)

  ln_kernel   <<<M_DIM / 4, 256, 0, stream>>>(x, ln_g, ln_b, xn);
  wconv_kernel<<<N_DIM, 256, 0, stream>>>(W, wb);
  gemm_gates  <<<dim3(M_DIM / BM, N_DIM / BN), 512, 0, stream>>>(xn, wb, bias, u_t, f_g, r_g);
  scan_pass1  <<<dim3(CH8 / 256, NSEG), 256, 0, stream>>>(f_g, u_t, Pseg, Eseg);
  scan_pass2  <<<CH / 128, 128, 0, stream>>>(Pseg, Eseg, c0, Cini, out + (size_t)M_DIM * DD);
  scan_pass3  <<<dim3(CH8 / 256, NSEG), 256, 0, stream>>>(f_g, u_t, r_g, x, xn, Cini, out);
}

// Round 15
// 202.542 us; speedup vs baseline: 1.0162x; 1.0162x over previous
//
#include <hip/hip_runtime.h>

#define L_DIM 2048
#define B_DIM 8
#define DD    1024
#define M_DIM 16384     // L*B
#define N_DIM 3072      // 3*D
#define K_DIM 1024
#define CH    8192      // B*D channels
#define CH8   1024      // CH/8 (vec8 units per l-step)
#define NSEG  128
#define LSEG  16
#define LN_EPS 1e-5f

typedef __attribute__((ext_vector_type(8))) short bf16x8;
typedef __attribute__((ext_vector_type(8))) unsigned short u16x8;
typedef __attribute__((ext_vector_type(4))) float f32x4;

__device__ __forceinline__ unsigned short f2bf(float f){
  unsigned u = __float_as_uint(f);
  u += 0x7fffu + ((u >> 16) & 1u);
  return (unsigned short)(u >> 16);
}
__device__ __forceinline__ float bf2f(unsigned short h){
  return __uint_as_float(((unsigned)h) << 16);
}
__device__ __forceinline__ float fsigmoid(float z){ return 1.0f/(1.0f + __expf(-z)); }
__device__ __forceinline__ float ftanh(float z){ return 1.0f - 2.0f/(1.0f + __expf(2.0f*z)); }

// ------- LayerNorm (blocks 0..4095) + W conversion (blocks 4096..7167) -------
// merged into one launch; both halves bit-identical to the previous kernels.
__global__ __launch_bounds__(256) void ln_wconv_kernel(const float* __restrict__ x,
                                                       const float* __restrict__ g,
                                                       const float* __restrict__ bta,
                                                       unsigned short* __restrict__ xn,
                                                       const float* __restrict__ W,
                                                       unsigned short* __restrict__ wb)
{
  int tid  = threadIdx.x;
  if (blockIdx.x >= M_DIM / 4) {
    // ---- wconv part: fp32 [3072,1024] -> bf16 same layout ----
    int gid = (blockIdx.x - M_DIM / 4) * 256 + tid;
    float4 v = ((const float4*)W)[gid];
    ushort4 o;
    o.x = f2bf(v.x); o.y = f2bf(v.y); o.z = f2bf(v.z); o.w = f2bf(v.w);
    ((ushort4*)wb)[gid] = o;
    return;
  }
  int wave = tid >> 6, lane = tid & 63;
  int row  = blockIdx.x * 4 + wave;
  const float4* xr = (const float4*)(x + (size_t)row * DD);
  float4 v[4];
  #pragma unroll
  for (int k = 0; k < 4; k++) v[k] = xr[lane + k * 64];
  float s = 0.f, sq = 0.f;
  #pragma unroll
  for (int k = 0; k < 4; k++) {
    s  += v[k].x + v[k].y + v[k].z + v[k].w;
    sq += v[k].x*v[k].x + v[k].y*v[k].y + v[k].z*v[k].z + v[k].w*v[k].w;
  }
  #pragma unroll
  for (int off = 32; off > 0; off >>= 1) {
    s  += __shfl_down(s,  off, 64);
    sq += __shfl_down(sq, off, 64);
  }
  s  = __shfl(s,  0, 64);
  sq = __shfl(sq, 0, 64);
  float mean = s * (1.0f / DD);
  float var  = sq * (1.0f / DD) - mean * mean;
  float rstd = rsqrtf(var + LN_EPS);
  ushort4* xo = (ushort4*)(xn + (size_t)row * DD);
  #pragma unroll
  for (int k = 0; k < 4; k++) {
    float4 gg = ((const float4*)g)[lane + k * 64];
    float4 bb = ((const float4*)bta)[lane + k * 64];
    ushort4 o;
    o.x = f2bf((v[k].x - mean) * rstd * gg.x + bb.x);
    o.y = f2bf((v[k].y - mean) * rstd * gg.y + bb.y);
    o.z = f2bf((v[k].z - mean) * rstd * gg.z + bb.z);
    o.w = f2bf((v[k].w - mean) * rstd * gg.w + bb.w);
    xo[lane + k * 64] = o;
  }
}

// ---------------- GEMM: ufr = xn * W^T + b, fused activations ----------------
// R14 base. ONE K-loop change: B split into two half-K buffers hA (k0..31) and
// hB (k32..63), 8 KB each (same 16 KB total, LDS stays 80 KB / 2 blocks/CU).
// Re-timed waits so every drained load aged >= one compute phase:
//   kk0(hA,A) -> WAIT_VM(4) [drains hB(t), aged kk0] -> SBAR1 -> stage hA(t+1)
//   kk1(hB,A) -> WAIT_VM(0) [drains A(t+1) 1-step-old + hA(t+1) aged kk1]
//   -> SBAR2 -> stage hB(t+1) + A(t+2)  (fly across next step)
// Removes R14's last exposed latency (fresh-B ~300cy/step). Bit-identical math.
// hA/hB rows are 64 B -> read swizzle slot = quad^(fm&3); staging source uses
// the same involution ((l&3)^((l>>2)&3)) so LDS dest stays linear.
#define BM 256
#define BN 128
#define BK 64
#define NT 16          // K_DIM / BK
#define LDP 136        // epilogue chunk leading dim (shorts)

#define GLDS16(gp, lp) __builtin_amdgcn_global_load_lds( \
    (const __attribute__((address_space(1))) void*)(gp), \
    (__attribute__((address_space(3))) void*)(lp), 16, 0, 0)

#define SBAR()   __builtin_amdgcn_s_barrier()
#define SCHED0() __builtin_amdgcn_sched_barrier(0)
#define WAIT_LGKM(N) do { asm volatile("s_waitcnt lgkmcnt(" #N ")" ::: "memory"); SCHED0(); } while(0)
#define WAIT_VM(N)   do { asm volatile("s_waitcnt vmcnt(" #N ")" ::: "memory"); SCHED0(); } while(0)

// raw ds_read_b128: invisible to alias analysis; ordering carried by the
// explicit lgkm/vm waits + barriers (volatile asm keeps mutual program order).
#define DSR(dst, addr, IMM) \
  asm volatile("ds_read_b128 %0, %1 offset:" #IMM : "=v"(dst) : "v"(addr))

#define MFMA(a, b, c) __builtin_amdgcn_mfma_f32_16x16x32_bf16((a), (b), (c), 0, 0, 0)

__global__ __launch_bounds__(512, 4) void gemm_gates(const unsigned short* __restrict__ A,
                                                     const unsigned short* __restrict__ Bw,
                                                     const float* __restrict__ bias,
                                                     unsigned short* __restrict__ u_t,
                                                     unsigned short* __restrict__ f_g,
                                                     unsigned short* __restrict__ r_g)
{
  // bytes: sA buf0 [0,32768) buf1 [32768,65536); hA [65536,73728); hB [73728,81920)
  __shared__ unsigned short smem[40960];   // 81,920 B
  const int tid  = threadIdx.x;
  const int wave = tid >> 6, lane = tid & 63;

  const int bm0 = blockIdx.x * BM;       // bx = bm fastest (R6/R11 locality)
  const int bn0 = blockIdx.y * BN;

  f32x4 zero = {0.f, 0.f, 0.f, 0.f};
  f32x4 acc[8][2];
  #pragma unroll
  for (int i = 0; i < 8; i++)
    #pragma unroll
    for (int j = 0; j < 2; j++) acc[i][j] = zero;

  const int q8  = lane >> 3;
  const int rr8 = lane & 7;
  const int sch = rr8 ^ q8;              // XOR swizzle source chunk (A staging)
  const unsigned short* a_lane = A + (size_t)(bm0 + wave * 32 + q8) * K_DIM + sch * 8;
  // B staging source (half-K tiles, rows of 64 B, involution (l&3)^((l>>2)&3)):
  const unsigned short* b_src = Bw + (size_t)(bn0 + wave * 16 + (lane >> 2)) * K_DIM
                                   + (size_t)(((lane & 3) ^ ((lane >> 2) & 3)) * 8);

  const int wm = (wave >> 2) * 128, wn = (wave & 3) * 32;   // 2M x 4N (R11)
  const int fm = lane & 15, quad = lane >> 4;
  const int f7 = fm & 7;

// stage A K-tile T into dbuf half BUF: 4 gload_lds per wave (HBM-class)
#define STAGE_A(BUF, T) do { \
  GLDS16(a_lane + (size_t)(T) * BK,                      &smem[(BUF)*16384 + (wave * 32 +  0) * BK]); \
  GLDS16(a_lane + (size_t)(T) * BK + (size_t) 8 * K_DIM, &smem[(BUF)*16384 + (wave * 32 +  8) * BK]); \
  GLDS16(a_lane + (size_t)(T) * BK + (size_t)16 * K_DIM, &smem[(BUF)*16384 + (wave * 32 + 16) * BK]); \
  GLDS16(a_lane + (size_t)(T) * BK + (size_t)24 * K_DIM, &smem[(BUF)*16384 + (wave * 32 + 24) * BK]); \
} while(0)

// stage B half-tiles (1 gload_lds per wave each; dest linear, 16 rows x 64 B)
#define STAGE_HA(T) GLDS16(b_src + (size_t)(T) * BK,      &smem[32768 + wave * 512])
#define STAGE_HB(T) GLDS16(b_src + (size_t)(T) * BK + 32, &smem[36864 + wave * 512])

// one kk half-step (counted-lgkm waits): 2 B + 8 A ds_read_b128,
// waits lgkm(2)/(0)/(2)/(0), 4x4 MFMA. Live frags: 6 (24 VGPR).
// B offsets within a half-buffer: ni*16 rows x 64 B = 1024 B.
#define COMPUTE_KK(AADDR, BADDR) do { \
  bf16x8 b0f, b1f, a0f, a1f, a2f, a3f; \
  DSR(b0f, (BADDR), 0); DSR(b1f, (BADDR), 1024); \
  DSR(a0f, (AADDR), 0);    DSR(a1f, (AADDR), 2048); \
  DSR(a2f, (AADDR), 4096); DSR(a3f, (AADDR), 6144); \
  WAIT_LGKM(2); \
  acc[0][0] = MFMA(a0f, b0f, acc[0][0]); acc[0][1] = MFMA(a0f, b1f, acc[0][1]); \
  acc[1][0] = MFMA(a1f, b0f, acc[1][0]); acc[1][1] = MFMA(a1f, b1f, acc[1][1]); \
  WAIT_LGKM(0); \
  acc[2][0] = MFMA(a2f, b0f, acc[2][0]); acc[2][1] = MFMA(a2f, b1f, acc[2][1]); \
  acc[3][0] = MFMA(a3f, b0f, acc[3][0]); acc[3][1] = MFMA(a3f, b1f, acc[3][1]); \
  DSR(a0f, (AADDR), 8192);  DSR(a1f, (AADDR), 10240); \
  DSR(a2f, (AADDR), 12288); DSR(a3f, (AADDR), 14336); \
  WAIT_LGKM(2); \
  acc[4][0] = MFMA(a0f, b0f, acc[4][0]); acc[4][1] = MFMA(a0f, b1f, acc[4][1]); \
  acc[5][0] = MFMA(a1f, b0f, acc[5][0]); acc[5][1] = MFMA(a1f, b1f, acc[5][1]); \
  WAIT_LGKM(0); \
  acc[6][0] = MFMA(a2f, b0f, acc[6][0]); acc[6][1] = MFMA(a2f, b1f, acc[6][1]); \
  acc[7][0] = MFMA(a3f, b0f, acc[7][0]); acc[7][1] = MFMA(a3f, b1f, acc[7][1]); \
} while(0)

  // fragment byte bases. A: XOR-swizzle slot0 = (quad^f7)*16, rows 128 B.
  const unsigned slot0 = (unsigned)((quad ^ f7) << 4);
  const unsigned aBase = (unsigned)((wm + fm) * 128) + slot0;
  // B half-buffer base: rows 64 B, slot = quad ^ (fm&3); hB = +8192 bytes.
  const unsigned bH = 65536u + (unsigned)((wn + fm) * 64)
                             + (unsigned)((quad ^ (fm & 3)) << 4);

  // ---- prologue: hA(0), hB(0), A(0), A(1); drain first 6 (hA0+hB0+A0) ----
  STAGE_HA(0);
  STAGE_HB(0);
  STAGE_A(0, 0);
  STAGE_A(1, 1);
  WAIT_VM(4);
  SBAR();

  #pragma unroll
  for (int t = 0; t < NT; ++t) {
    const int cb = t & 1;
    const unsigned cbB = (unsigned)(cb * 32768);
    // kk0: reads hA(t) + A(t); hB(t) ages under this compute
    COMPUTE_KK(cbB + aBase, bH);
    if (t < NT - 1) { WAIT_VM(4); }        // drains hB(t) (aged ~kk0); leaves A(t+1)
    else           { WAIT_VM(0); }         // tail: only hB(15) outstanding
    SBAR();                                // publish hB(t); hA reads complete
    if (t + 1 < NT) STAGE_HA(t + 1);       // hA free after kk0
    SCHED0();
    // kk1: reads hB(t) + A(t); hA(t+1) ages under this compute
    COMPUTE_KK((cbB + aBase) ^ 64u, bH + 8192u);
    WAIT_VM(0);                            // drains A(t+1) [1 step old] + hA(t+1) [aged kk1]
    SBAR();                                // publish hA(t+1), A(t+1); hB/A[cb] reads done
    if (t + 1 < NT) STAGE_HB(t + 1);       // 1 load, flies across next step
    if (t + 2 < NT) STAGE_A(cb, t + 2);    // 4 loads, fly across next step
    SCHED0();
  }
  __syncthreads();

  const int slice = bn0 >> 10;
  const int nd0   = bn0 & 1023;
  unsigned short* dst = (slice == 0) ? u_t : ((slice == 1) ? f_g : r_g);

  // two-chunk epilogue (R14 verbatim): rows [h*128, h*128+128) in 128*LDP shorts
  #pragma unroll
  for (int h = 0; h < 2; ++h) {
    if ((wave >> 2) == h) {
      #pragma unroll
      for (int ni = 0; ni < 2; ni++) {
        int lcol = wn + ni * 16 + fm;
        float bia = bias[bn0 + lcol];
        #pragma unroll
        for (int mi = 0; mi < 8; mi++) {
          #pragma unroll
          for (int reg = 0; reg < 4; reg++) {
            int lrow = mi * 16 + quad * 4 + reg;       // 0..127 within chunk
            float v = acc[mi][ni][reg] + bia;
            float act = (slice == 0) ? ftanh(v) : fsigmoid(v);
            smem[lrow * LDP + lcol] = f2bf(act);
          }
        }
      }
    }
    __syncthreads();
    #pragma unroll
    for (int it = 0; it < 4; ++it) {
      int row = it * 32 + (tid >> 4);                  // 0..127
      int cc  = (tid & 15) * 8;                        // 0..120
      u16x8 v = *(const u16x8*)&smem[row * LDP + cc];
      *(u16x8*)(dst + (size_t)(bm0 + h * 128 + row) * DD + nd0 + cc) = v;
    }
    __syncthreads();
  }
}

// ---- scan pass 1: per-segment affine summary, vec8 channels, 16B loads ----
// segment = 16 l-steps; P,E stored bf16 [NSEG][CH]
__global__ __launch_bounds__(256) void scan_pass1(const unsigned short* __restrict__ f_g,
                                                  const unsigned short* __restrict__ u_t,
                                                  unsigned short* __restrict__ P,
                                                  unsigned short* __restrict__ E)
{
  int vc8 = blockIdx.x * 256 + threadIdx.x;   // 0..1023
  int seg = blockIdx.y;                       // 0..127
  const u16x8* f8 = (const u16x8*)f_g;
  const u16x8* u8 = (const u16x8*)u_t;
  size_t g = (size_t)(seg * LSEG) * CH8 + vc8;
  float p[8], e[8];
  #pragma unroll
  for (int k = 0; k < 8; k++) { p[k] = 1.f; e[k] = 0.f; }
  #pragma unroll 4
  for (int i = 0; i < LSEG; i++) {
    u16x8 ff = f8[g];
    u16x8 uu = u8[g];
    #pragma unroll
    for (int k = 0; k < 8; k++) {
      float fv = bf2f(ff[k]);
      e[k] = fv * e[k] + (1.f - fv) * bf2f(uu[k]);
      p[k] *= fv;
    }
    g += CH8;
  }
  u16x8 pv, ev;
  #pragma unroll
  for (int k = 0; k < 8; k++) { pv[k] = f2bf(p[k]); ev[k] = f2bf(e[k]); }
  ((u16x8*)P)[(size_t)seg * CH8 + vc8] = pv;
  ((u16x8*)E)[(size_t)seg * CH8 + vc8] = ev;
}

// ---- scan pass 2: scan 128 segment summaries per channel ----
__global__ __launch_bounds__(128) void scan_pass2(const unsigned short* __restrict__ P,
                                                  const unsigned short* __restrict__ E,
                                                  const float* __restrict__ c0,
                                                  float* __restrict__ Cini,
                                                  float* __restrict__ lastc)
{
  int ch = blockIdx.x * 128 + threadIdx.x;    // 64 blocks x 128
  float c = c0[ch];
  #pragma unroll 8
  for (int s = 0; s < NSEG; s++) {
    Cini[(size_t)s * CH + ch] = c;
    c = bf2f(P[(size_t)s * CH + ch]) * c + bf2f(E[(size_t)s * CH + ch]);
  }
  lastc[ch] = c;
}

// ---- scan pass 3: replay with true init + fused output, vec8, 16B loads ----
__global__ __launch_bounds__(256) void scan_pass3(const unsigned short* __restrict__ f_g,
                                                  const unsigned short* __restrict__ u_t,
                                                  const unsigned short* __restrict__ r_g,
                                                  const float* __restrict__ x,
                                                  const unsigned short* __restrict__ xn,
                                                  const float* __restrict__ Cini,
                                                  float* __restrict__ out)
{
  int vc8 = blockIdx.x * 256 + threadIdx.x;   // 0..1023
  int seg = blockIdx.y;                       // 0..127
  const u16x8* f8 = (const u16x8*)f_g;
  const u16x8* u8 = (const u16x8*)u_t;
  const u16x8* r8 = (const u16x8*)r_g;
  const u16x8* n8 = (const u16x8*)xn;
  const float4* x4 = (const float4*)x;
  float4* o4 = (float4*)out;
  float c[8];
  {
    const float4* C4 = (const float4*)Cini;
    size_t ci = (size_t)seg * (CH / 4) + (size_t)vc8 * 2;
    float4 ca = C4[ci], cb = C4[ci + 1];
    c[0]=ca.x; c[1]=ca.y; c[2]=ca.z; c[3]=ca.w;
    c[4]=cb.x; c[5]=cb.y; c[6]=cb.z; c[7]=cb.w;
  }
  size_t g = (size_t)(seg * LSEG) * CH8 + vc8;
  #pragma unroll 2
  for (int i = 0; i < LSEG; i++) {
    u16x8 ff = f8[g];
    u16x8 uu = u8[g];
    u16x8 rr = r8[g];
    u16x8 nn = n8[g];
    size_t xi = g * 2;                 // float4 index (8 floats = 2 float4)
    float4 xa = x4[xi], xb = x4[xi + 1];
    float ov[8];
    #pragma unroll
    for (int k = 0; k < 8; k++) {
      float fv = bf2f(ff[k]);
      c[k] = fv * c[k] + (1.f - fv) * bf2f(uu[k]);
      float rv = bf2f(rr[k]);
      ov[k] = rv * ftanh(c[k]) + (1.f - rv) * bf2f(nn[k]);
    }
    o4[xi]     = (float4){xa.x + ov[0], xa.y + ov[1], xa.z + ov[2], xa.w + ov[3]};
    o4[xi + 1] = (float4){xb.x + ov[4], xb.y + ov[5], xb.z + ov[6], xb.w + ov[7]};
    g += CH8;
  }
}

extern "C" void kernel_launch(void* const* d_in, const int* in_sizes, int n_in,
                              void* d_out, int out_size, void* d_ws, size_t ws_size,
                              hipStream_t stream) {
  const float* x    = (const float*)d_in[0];
  const float* c0   = (const float*)d_in[1];
  const float* W    = (const float*)d_in[2];
  const float* bias = (const float*)d_in[3];
  const float* ln_g = (const float*)d_in[4];
  const float* ln_b = (const float*)d_in[5];
  float* out = (float*)d_out;

  char* ws = (char*)d_ws;
  unsigned short* xn  = (unsigned short*)(ws);                 // 33,554,432 B
  unsigned short* wb  = (unsigned short*)(ws + 33554432ULL);   //  6,291,456 B (dead after gemm)
  unsigned short* u_t = (unsigned short*)(ws + 39845888ULL);   // 33,554,432 B
  unsigned short* f_g = (unsigned short*)(ws + 73400320ULL);   // 33,554,432 B
  unsigned short* r_g = (unsigned short*)(ws + 106954752ULL);  // 33,554,432 B
  // P,E (bf16, 2 MB each) reuse wb's region after gemm completes:
  unsigned short* Pseg = (unsigned short*)(ws + 33554432ULL);  // 2,097,152 B
  unsigned short* Eseg = (unsigned short*)(ws + 35651584ULL);  // 2,097,152 B
  float* Cini = (float*)(ws + 140509184ULL);                   // 4,194,304 B (ends 144,703,488)

  ln_wconv_kernel<<<M_DIM / 4 + N_DIM, 256, 0, stream>>>(x, ln_g, ln_b, xn, W, wb);
  gemm_gates  <<<dim3(M_DIM / BM, N_DIM / BN), 512, 0, stream>>>(xn, wb, bias, u_t, f_g, r_g);
  scan_pass1  <<<dim3(CH8 / 256, NSEG), 256, 0, stream>>>(f_g, u_t, Pseg, Eseg);
  scan_pass2  <<<CH / 128, 128, 0, stream>>>(Pseg, Eseg, c0, Cini, out + (size_t)M_DIM * DD);
  scan_pass3  <<<dim3(CH8 / 256, NSEG), 256, 0, stream>>>(f_g, u_t, r_g, x, xn, Cini, out);
}